// Round 1
// 234.167 us; speedup vs baseline: 1.0658x; 1.0658x over previous
//
#include <hip/hip_runtime.h>

typedef unsigned short ushort_t;
typedef unsigned int uint_t;

#define NB 4
#define NC 128
#define NH 128
#define NW 128
#define NPIX 65536   // NB*NH*NW
#define NMID 32
#define NKK 49
#define NK 392
#define NKP 400      // NK padded to 25 n-tiles of 16
#define NO 256
#define LN_EPS 1e-6f

typedef __attribute__((ext_vector_type(8))) short short8;
typedef __attribute__((ext_vector_type(4))) float floatx4;

__device__ __forceinline__ float bf2f(ushort_t u) {
    union { uint_t i; float f; } v; v.i = ((uint_t)u) << 16; return v.f;
}
__device__ __forceinline__ float bf2f_lo(uint_t u) {
    union { uint_t i; float f; } v; v.i = u << 16; return v.f;
}
__device__ __forceinline__ float bf2f_hi(uint_t u) {
    union { uint_t i; float f; } v; v.i = u & 0xffff0000u; return v.f;
}
__device__ __forceinline__ ushort_t f2bf(float f) {
    union { float f; uint_t i; } v; v.f = f;
    uint_t x = v.i;
    uint_t r = (x + 0x7FFFu + ((x >> 16) & 1u)) >> 16;
    return (ushort_t)r;
}
__device__ __forceinline__ float gelu_f(float x) {
    return 0.5f * x * (1.0f + erff(x * 0.70710678118654752f));
}
__device__ __forceinline__ float ldin(const void* p, int i, int isf32) {
    return isf32 ? ((const float*)p)[i] : bf2f(((const ushort_t*)p)[i]);
}

// ---------------------------------------------------------------------------
__global__ void kdetect(const uint_t* __restrict__ xw, int* __restrict__ flag) {
    int lane = threadIdx.x;
    int cnt = 0;
    for (int j = 0; j < 8; j++) {
        uint_t w = xw[lane * 8 + j];
        uint_t e = (w >> 7) & 0xffu;
        if (e >= 110u && e <= 135u) cnt++;
    }
    for (int d = 1; d < 64; d <<= 1) cnt += __shfl_xor(cnt, d);
    if (lane == 0) flag[0] = (cnt < 256) ? 1 : 0;
}

__global__ void ksentinel(uint_t* __restrict__ out, int nwords) {
    int i = blockIdx.x * 256 + threadIdx.x;
    if (i < nwords) out[i] = 0x40004000u;
}

// ---------------------------------------------------------------------------
// K0a: transpose x (B,C,H,W) -> xT (B,H,W,C) canonical bf16.
// ---------------------------------------------------------------------------
__global__ __launch_bounds__(256) void ktrans(const void* __restrict__ x,
                                              ushort_t* __restrict__ xT,
                                              const int* __restrict__ flag) {
    int isf32 = flag[0];
    int b = blockIdx.z, h = blockIdx.y;
    int wchunk = blockIdx.x & 1, cchunk = blockIdx.x >> 1;
    int w0 = wchunk << 6, c0 = cchunk << 5;
    __shared__ ushort_t tile[32][66];
    int tx = threadIdx.x & 63, ty = threadIdx.x >> 6;
    for (int r = 0; r < 32; r += 4) {
        int idx = (((b * NC + c0 + r + ty) * NH) + h) * NW + w0 + tx;
        tile[r + ty][tx] = isf32 ? f2bf(((const float*)x)[idx])
                                 : ((const ushort_t*)x)[idx];
    }
    __syncthreads();
    int cc = threadIdx.x & 31, wq = threadIdx.x >> 5;
    for (int pp = 0; pp < 64; pp += 8) {
        int wx = pp + wq;
        xT[((size_t)((b * NH + h) * NW) + w0 + wx) * NC + c0 + cc] = tile[cc][wx];
    }
}

// ---------------------------------------------------------------------------
// K0b: param prep (w1b/w2b for k1a; small vectors -> fp32).
// ---------------------------------------------------------------------------
__global__ __launch_bounds__(256) void kprep(const void* w1, const void* w2,
                                             const void* b1, const void* b2,
                                             const void* ln1w, const void* ln1b,
                                             const void* ln2w, const void* ln2b,
                                             const void* map_b,
                                             const void* ln3w, const void* ln3b,
                                             const int* __restrict__ flag,
                                             ushort_t* __restrict__ w1b,
                                             ushort_t* __restrict__ w2b,
                                             float* __restrict__ b1f,
                                             float* __restrict__ b2f,
                                             float* __restrict__ ln1wf,
                                             float* __restrict__ ln1bf,
                                             float* __restrict__ ln2wf,
                                             float* __restrict__ ln2bf,
                                             float* __restrict__ mbf,
                                             float* __restrict__ ln3wf,
                                             float* __restrict__ ln3bf) {
    int isf32 = flag[0];
    int i = blockIdx.x * 256 + threadIdx.x;
    if (i < NMID * NC) w1b[i] = f2bf(ldin(w1, i, isf32));
    if (i < NKP * NMID) w2b[i] = (i < NK * NMID) ? f2bf(ldin(w2, i, isf32))
                                                 : (ushort_t)0;
    if (i < NMID) b1f[i] = ldin(b1, i, isf32);
    if (i < NKP)  b2f[i] = (i < NK) ? ldin(b2, i, isf32) : 0.f;
    if (i < NC) { ln1wf[i] = ldin(ln1w, i, isf32); ln1bf[i] = ldin(ln1b, i, isf32); }
    if (i < NO) {
        ln2wf[i] = ldin(ln2w, i, isf32); ln2bf[i] = ldin(ln2b, i, isf32);
        mbf[i]   = ldin(map_b, i, isf32);
        ln3wf[i] = ldin(ln3w, i, isf32); ln3bf[i] = ldin(ln3b, i, isf32);
    }
}

// ---------------------------------------------------------------------------
// KFRAG: repack conv_w/map_w into per-wave MFMA-fragment order for k23:
// chunk id cid = [w:2][kb:2][br:1][nt:2][lane:6], chunk = 8 bf16 = 16 B.
// k23's B load becomes base + lane*16 -> one coalesced dwordx4 per frag.
// grid 32 x 256.
// ---------------------------------------------------------------------------
__global__ __launch_bounds__(256) void kfrag(const void* conv_w, const void* map_w,
                                             const int* __restrict__ flag,
                                             ushort_t* __restrict__ wfrag) {
    int isf32 = flag[0];
    int cid = blockIdx.x * 256 + threadIdx.x;   // [0, 8192)
    int lane = cid & 63, nt = (cid >> 6) & 3, br = (cid >> 8) & 1;
    int kb = (cid >> 9) & 3, w = (cid >> 11) & 3;
    int o = w * 64 + nt * 16 + (lane & 15);
    int ch0 = kb * 32 + (lane >> 4) * 8;
    const void* src = br ? map_w : conv_w;
    ushort_t* dst = wfrag + (size_t)cid * 8;
#pragma unroll
    for (int j = 0; j < 8; j++)
        dst[j] = f2bf(ldin(src, o * NC + ch0 + j, isf32));
}

// ---------------------------------------------------------------------------
// K1a: wk producer (unchanged). grid 1024, block 256.
// ---------------------------------------------------------------------------
__global__ __launch_bounds__(256) void k1a(const ushort_t* __restrict__ xT,
                                           const ushort_t* __restrict__ w1b,
                                           const float* __restrict__ b1f,
                                           const ushort_t* __restrict__ w2b,
                                           const float* __restrict__ b2f,
                                           ushort_t* __restrict__ wkT) {
    __shared__ ushort_t midbuf[64 * 32];
    __shared__ ushort_t wkstage[NKP * 66];

    int t = threadIdx.x;
    int lane = t & 63;
    int w = __builtin_amdgcn_readfirstlane(t >> 6);
    int l16 = lane & 15, quad = lane >> 4;
    int tileid = blockIdx.x;
    int tilex = tileid & 15, tiley = (tileid >> 4) & 15, b = tileid >> 8;
    int h0 = tiley * 8, w0 = tilex * 8;

    int lpx_a = 16 * w + l16;
    int py = lpx_a >> 3, pxx = lpx_a & 7;
    const ushort_t* abase = xT + (size_t)((b * NH + h0 + py) * NW + w0 + pxx) * NC + quad * 8;
    floatx4 am0 = (floatx4)0.f, am1 = (floatx4)0.f;
#pragma unroll
    for (int kb = 0; kb < 4; kb++) {
        short8 a   = *(const short8*)(abase + kb * 32);
        short8 b0  = *(const short8*)(w1b + (l16) * NC + kb * 32 + quad * 8);
        short8 b1v = *(const short8*)(w1b + (16 + l16) * NC + kb * 32 + quad * 8);
        am0 = __builtin_amdgcn_mfma_f32_16x16x32_bf16(a, b0, am0, 0, 0, 0);
        am1 = __builtin_amdgcn_mfma_f32_16x16x32_bf16(a, b1v, am1, 0, 0, 0);
    }
    {
        float bia0 = b1f[l16], bia1 = b1f[16 + l16];
#pragma unroll
        for (int r = 0; r < 4; r++) {
            int m = 16 * w + quad * 4 + r;
            midbuf[m * 32 + l16]      = f2bf(fmaxf(am0[r] + bia0, 0.f));
            midbuf[m * 32 + 16 + l16] = f2bf(fmaxf(am1[r] + bia1, 0.f));
        }
    }
    __syncthreads();

    short8 aM = *(const short8*)(midbuf + (16 * w + l16) * 32 + quad * 8);
#pragma unroll
    for (int nt = 0; nt < 25; nt++) {
        int n = nt * 16 + l16;
        short8 bw = *(const short8*)(w2b + n * 32 + quad * 8);
        floatx4 c = __builtin_amdgcn_mfma_f32_16x16x32_bf16(aM, bw, (floatx4)0.f, 0, 0, 0);
        float bias = b2f[n];
#pragma unroll
        for (int r = 0; r < 4; r++)
            wkstage[n * 66 + 16 * w + quad * 4 + r] = f2bf(c[r] + bias);
    }
    __syncthreads();

    int krow = t >> 5, px2 = t & 31;
    for (int it = 0; it < 50; it++) {
        int k = it * 8 + krow;
        uint_t v = *(const uint_t*)&wkstage[k * 66 + 2 * px2];
        *(uint_t*)&wkT[(size_t)k * NPIX + tileid * 64 + 2 * px2] = v;
    }
}

// ---------------------------------------------------------------------------
// K1b v3 (unchanged from round 8). grid 1024, block 512.
// ---------------------------------------------------------------------------
__global__ __launch_bounds__(512) void k1b(const ushort_t* __restrict__ xT,
                                           const ushort_t* __restrict__ wkT,
                                           const float* __restrict__ ln1wf,
                                           const float* __restrict__ ln1bf,
                                           ushort_t* __restrict__ y1) {
    __shared__ __align__(16) char smem[50432];
    uint4* x8   = (uint4*)smem;
    float* sred = (float*)smem;

    int t = threadIdx.x;
    int lane = t & 63;
    int w = __builtin_amdgcn_readfirstlane(t >> 6);
    int tileid = blockIdx.x;
    int tilex = tileid & 15, tiley = (tileid >> 4) & 15, b = tileid >> 8;
    int h0 = tiley * 8, w0 = tilex * 8;
    int py = lane >> 3, pxx = lane & 7;

    const ushort_t* wkbase = wkT + (size_t)(w * NKK) * NPIX + tileid * 64 + lane;
    uint_t wkp[25];
#pragma unroll
    for (int j = 0; j < 24; j++) {
        uint_t lo = wkbase[(size_t)(2 * j) * NPIX];
        uint_t hi = wkbase[(size_t)(2 * j + 1) * NPIX];
        wkp[j] = lo | (hi << 16);
    }
    wkp[24] = wkbase[(size_t)48 * NPIX];

    for (int it = 0; it < 7; it++) {
        int idx = it * 512 + t;
        if (idx < 3136) {
            int oct = idx & 15, hp = idx >> 4;
            int hy = hp / 14, hx = hp - hy * 14;
            int gh = h0 + hy - 3, gw = w0 + hx - 3;
            uint4 v = make_uint4(0u, 0u, 0u, 0u);
            if ((unsigned)gh < (unsigned)NH && (unsigned)gw < (unsigned)NW) {
                v = *(const uint4*)&xT[(size_t)((b * NH + gh) * NW + gw) * NC + 8 * oct];
            }
            x8[oct * 197 + hp] = v;
        }
    }
    __syncthreads();

    int base0 = py * 14 + pxx;
    float a[16];
#pragma unroll
    for (int j = 0; j < 16; j++) a[j] = 0.f;

#pragma unroll
    for (int tap = 0; tap < NKK; tap++) {
        float wkf = (tap & 1) ? bf2f((ushort_t)(wkp[tap >> 1] >> 16))
                              : bf2f((ushort_t)(wkp[tap >> 1] & 0xffffu));
        int xa = base0 + (tap / 7) * 14 + (tap % 7);
        uint4 u0 = x8[(2 * w) * 197 + xa];
        uint4 u1 = x8[(2 * w + 1) * 197 + xa];
        a[0]  = fmaf(wkf, bf2f_lo(u0.x), a[0]);
        a[1]  = fmaf(wkf, bf2f_hi(u0.x), a[1]);
        a[2]  = fmaf(wkf, bf2f_lo(u0.y), a[2]);
        a[3]  = fmaf(wkf, bf2f_hi(u0.y), a[3]);
        a[4]  = fmaf(wkf, bf2f_lo(u0.z), a[4]);
        a[5]  = fmaf(wkf, bf2f_hi(u0.z), a[5]);
        a[6]  = fmaf(wkf, bf2f_lo(u0.w), a[6]);
        a[7]  = fmaf(wkf, bf2f_hi(u0.w), a[7]);
        a[8]  = fmaf(wkf, bf2f_lo(u1.x), a[8]);
        a[9]  = fmaf(wkf, bf2f_hi(u1.x), a[9]);
        a[10] = fmaf(wkf, bf2f_lo(u1.y), a[10]);
        a[11] = fmaf(wkf, bf2f_hi(u1.y), a[11]);
        a[12] = fmaf(wkf, bf2f_lo(u1.z), a[12]);
        a[13] = fmaf(wkf, bf2f_hi(u1.z), a[13]);
        a[14] = fmaf(wkf, bf2f_lo(u1.w), a[14]);
        a[15] = fmaf(wkf, bf2f_hi(u1.w), a[15]);
    }
    __syncthreads();

    float s = 0.f, sq = 0.f;
#pragma unroll
    for (int j = 0; j < 16; j++) { s += a[j]; sq += a[j] * a[j]; }
    sred[(w * 64 + lane) * 2]     = s;
    sred[(w * 64 + lane) * 2 + 1] = sq;
    __syncthreads();
    float ts = 0.f, tq = 0.f;
#pragma unroll
    for (int r = 0; r < 8; r++) {
        ts += sred[(r * 64 + lane) * 2];
        tq += sred[(r * 64 + lane) * 2 + 1];
    }
    float mean = ts * (1.0f / NC);
    float var = tq * (1.0f / NC) - mean * mean;
    float rstd = rsqrtf(var + LN_EPS);

    int p = (b * NH + h0 + py) * NW + w0 + pxx;
    uint_t pk[8];
#pragma unroll
    for (int j = 0; j < 8; j++) {
        int c0 = 16 * w + 2 * j;
        float g0 = gelu_f((a[2 * j] - mean) * rstd * ln1wf[c0] + ln1bf[c0]);
        float g1 = gelu_f((a[2 * j + 1] - mean) * rstd * ln1wf[c0 + 1] + ln1bf[c0 + 1]);
        pk[j] = (uint_t)f2bf(g0) | ((uint_t)f2bf(g1) << 16);
    }
    uint4* dst = (uint4*)(y1 + (size_t)p * NC + 16 * w);
    dst[0] = make_uint4(pk[0], pk[1], pk[2], pk[3]);
    dst[1] = make_uint4(pk[4], pk[5], pk[6], pk[7]);
}

// ---------------------------------------------------------------------------
// K1 fused fallback — used only if ws too small for wkT.
// ---------------------------------------------------------------------------
__global__ __launch_bounds__(64) void k1_fused(const ushort_t* __restrict__ xT,
                                               const ushort_t* __restrict__ w1b,
                                               const float* __restrict__ b1f,
                                               const ushort_t* __restrict__ w2b,
                                               const float* __restrict__ b2f,
                                               const float* __restrict__ ln1wf,
                                               const float* __restrict__ ln1bf,
                                               ushort_t* __restrict__ y1) {
    __shared__ ushort_t midbuf[16 * 32];
    __shared__ ushort_t wkbuf[16 * NKP];

    int lane = threadIdx.x;
    int l16 = lane & 15, quad = lane >> 4;
    int b = blockIdx.z;
    int h0 = blockIdx.y * 2, w0 = blockIdx.x * 8;

    int Pa = (b * NH + h0 + (l16 >> 3)) * NW + w0 + (l16 & 7);
    const ushort_t* abase = xT + (size_t)Pa * NC + quad * 8;
    floatx4 am0 = (floatx4)0.f, am1 = (floatx4)0.f;
#pragma unroll
    for (int kb = 0; kb < 4; kb++) {
        short8 a   = *(const short8*)(abase + kb * 32);
        short8 b0  = *(const short8*)(w1b + (l16) * NC + kb * 32 + quad * 8);
        short8 b1v = *(const short8*)(w1b + (16 + l16) * NC + kb * 32 + quad * 8);
        am0 = __builtin_amdgcn_mfma_f32_16x16x32_bf16(a, b0, am0, 0, 0, 0);
        am1 = __builtin_amdgcn_mfma_f32_16x16x32_bf16(a, b1v, am1, 0, 0, 0);
    }
    {
        float bia0 = b1f[l16], bia1 = b1f[16 + l16];
#pragma unroll
        for (int r = 0; r < 4; r++) {
            int m = quad * 4 + r;
            midbuf[m * 32 + l16]      = f2bf(fmaxf(am0[r] + bia0, 0.f));
            midbuf[m * 32 + 16 + l16] = f2bf(fmaxf(am1[r] + bia1, 0.f));
        }
    }
    __syncthreads();

    short8 aM = *(const short8*)(midbuf + l16 * 32 + quad * 8);
#pragma unroll
    for (int nt = 0; nt < 25; nt++) {
        int n = nt * 16 + l16;
        short8 bw = *(const short8*)(w2b + n * 32 + quad * 8);
        floatx4 c = __builtin_amdgcn_mfma_f32_16x16x32_bf16(aM, bw, (floatx4)0.f, 0, 0, 0);
        float bias = b2f[n];
#pragma unroll
        for (int r = 0; r < 4; r++)
            wkbuf[(quad * 4 + r) * NKP + n] = f2bf(c[r] + bias);
    }
    __syncthreads();

    int g = lane >> 3;
    float l1w0 = ln1wf[2 * lane], l1w1 = ln1wf[2 * lane + 1];
    float l1b0 = ln1bf[2 * lane], l1b1 = ln1bf[2 * lane + 1];

    for (int i = 0; i < 16; i++) {
        int hh0 = h0 + (i >> 3), ww0 = w0 + (i & 7);
        int p = (b * NH + hh0) * NW + ww0;
        const ushort_t* wkrow = wkbuf + i * NKP + g * NKK;
        float a0 = 0.f, a1 = 0.f;
#pragma unroll
        for (int dy = -3; dy <= 3; dy++) {
            int hh = hh0 + dy;
            if ((unsigned)hh >= (unsigned)NH) continue;
#pragma unroll
            for (int dx = -3; dx <= 3; dx++) {
                int ww = ww0 + dx;
                if ((unsigned)ww >= (unsigned)NW) continue;
                float wkv = bf2f(wkrow[(dy + 3) * 7 + (dx + 3)]);
                uint_t xp = *(const uint_t*)(xT + ((size_t)(p + dy * NW + dx)) * NC + 2 * lane);
                a0 = fmaf(wkv, bf2f((ushort_t)(xp & 0xffffu)), a0);
                a1 = fmaf(wkv, bf2f((ushort_t)(xp >> 16)), a1);
            }
        }
        float s = a0 + a1, sq = a0 * a0 + a1 * a1;
#pragma unroll
        for (int d = 1; d < 64; d <<= 1) {
            s  += __shfl_xor(s, d);
            sq += __shfl_xor(sq, d);
        }
        float mean = s * (1.0f / NC);
        float var = sq * (1.0f / NC) - mean * mean;
        float rstd = rsqrtf(var + LN_EPS);
        float g0 = gelu_f((a0 - mean) * rstd * l1w0 + l1b0);
        float g1 = gelu_f((a1 - mean) * rstd * l1w1 + l1b1);
        uint_t pk = (uint_t)f2bf(g0) | ((uint_t)f2bf(g1) << 16);
        *(uint_t*)(y1 + (size_t)p * NC + 2 * lane) = pk;
    }
}

// ---------------------------------------------------------------------------
// K23 v5: wave-autonomous tiling. Each wave owns 16 px x 256 o (both
// branches) -> LN stats are wave-internal (4 shfl_xor steps), ZERO
// __syncthreads. 128 independent MFMAs per wave (acc 2x16 floatx4 = 128
// VGPRs) deepen the latency-hiding chain. Per-wave 1.25KB padded LDS
// transpose (double-buffered, same-wave DS order + lgkmcnt fence) for
// coalesced float4/uint2 stores. Block 256 = 4 waves = 64 px; grid 1024.
// ---------------------------------------------------------------------------
__global__ __launch_bounds__(256, 2) void k23(const ushort_t* __restrict__ y1,
                                              const ushort_t* __restrict__ xT,
                                              const ushort_t* __restrict__ wfrag,
                                              const float* __restrict__ mbf,
                                              const float* __restrict__ ln2wf,
                                              const float* __restrict__ ln2bf,
                                              const float* __restrict__ ln3wf,
                                              const float* __restrict__ ln3bf,
                                              void* __restrict__ out,
                                              const int* __restrict__ flag) {
    // per-wave: 2 buffers x 16 o-rows x (16 px + 4 pad) floats
    __shared__ __align__(16) float tbuf[4 * 2 * 320];

    int isf32 = flag[0];
    int t = threadIdx.x;
    int lane = t & 63;
    int w = __builtin_amdgcn_readfirstlane(t >> 6);
    int quad = lane >> 4, l16 = lane & 15;

    int P0 = blockIdx.x * 64;
    int pw = P0 + w * 16;                       // this wave's first pixel
    const ushort_t* aYp = y1 + (size_t)(pw + l16) * NC + quad * 8;
    const ushort_t* aXp = xT + (size_t)(pw + l16) * NC + quad * 8;
    const ushort_t* bb  = wfrag + (size_t)lane * 8;

    floatx4 accC[16], accM[16];
#pragma unroll
    for (int n4 = 0; n4 < 16; n4++) { accC[n4] = (floatx4)0.f; accM[n4] = (floatx4)0.f; }

#pragma unroll
    for (int kb = 0; kb < 4; kb++) {
        short8 aY = *(const short8*)(aYp + kb * 32);
        short8 aX = *(const short8*)(aXp + kb * 32);
#pragma unroll
        for (int n4 = 0; n4 < 16; n4++) {
            // chunk index = ow*2048 + kb*512 + br*256 + ntl*64 + lane, chunk=8 elems
            const ushort_t* bp = bb + (size_t)(((n4 >> 2) * 2048 + kb * 512 + (n4 & 3) * 64)) * 8;
            short8 bc = *(const short8*)bp;
            short8 bm = *(const short8*)(bp + 256 * 8);
            accC[n4] = __builtin_amdgcn_mfma_f32_16x16x32_bf16(aY, bc, accC[n4], 0, 0, 0);
            accM[n4] = __builtin_amdgcn_mfma_f32_16x16x32_bf16(aX, bm, accM[n4], 0, 0, 0);
        }
    }

    // map-branch bias (before LN3 stats)
#pragma unroll
    for (int n4 = 0; n4 < 16; n4++) {
        float mb = mbf[n4 * 16 + l16];
#pragma unroll
        for (int r = 0; r < 4; r++) accM[n4][r] += mb;
    }

    // LN stats per px (px = quad*4 + r): 16-reg partial sums, then butterfly
    // over the 16 o-lanes (d<16 stays inside each l16 group).
    floatx4 s1 = (floatx4)0.f, q1 = (floatx4)0.f, s2 = (floatx4)0.f, q2 = (floatx4)0.f;
#pragma unroll
    for (int n4 = 0; n4 < 16; n4++)
#pragma unroll
        for (int r = 0; r < 4; r++) {
            float a = accC[n4][r], m = accM[n4][r];
            s1[r] += a; q1[r] += a * a;
            s2[r] += m; q2[r] += m * m;
        }
#pragma unroll
    for (int d = 1; d < 16; d <<= 1) {
#pragma unroll
        for (int r = 0; r < 4; r++) {
            s1[r] += __shfl_xor(s1[r], d);
            q1[r] += __shfl_xor(q1[r], d);
            s2[r] += __shfl_xor(s2[r], d);
            q2[r] += __shfl_xor(q2[r], d);
        }
    }
    floatx4 m1, r1, m2, r2;
#pragma unroll
    for (int r = 0; r < 4; r++) {
        m1[r] = s1[r] * (1.0f / NO);
        r1[r] = rsqrtf(q1[r] * (1.0f / NO) - m1[r] * m1[r] + LN_EPS);
        m2[r] = s2[r] * (1.0f / NO);
        r2[r] = rsqrtf(q2[r] * (1.0f / NO) - m2[r] * m2[r] + LN_EPS);
    }

    int batch = pw >> 14;
    int plocal = pw & 16383;
    int o_l = lane >> 2, px4 = (lane & 3) * 4;
    float* tb0 = tbuf + w * 640;

#pragma unroll
    for (int n4 = 0; n4 < 16; n4++) {
        int o = n4 * 16 + l16;
        float l2w = ln2wf[o], l2b = ln2bf[o];
        float l3w = ln3wf[o], l3b = ln3bf[o];
        float* tb = tb0 + (n4 & 1) * 320;
        float4 gv;
        {
            float v1, v2;
            v1 = (accC[n4][0] - m1[0]) * r1[0] * l2w + l2b;
            v2 = (accM[n4][0] - m2[0]) * r2[0] * l3w + l3b;
            gv.x = gelu_f(v1 + v2);
            v1 = (accC[n4][1] - m1[1]) * r1[1] * l2w + l2b;
            v2 = (accM[n4][1] - m2[1]) * r2[1] * l3w + l3b;
            gv.y = gelu_f(v1 + v2);
            v1 = (accC[n4][2] - m1[2]) * r1[2] * l2w + l2b;
            v2 = (accM[n4][2] - m2[2]) * r2[2] * l3w + l3b;
            gv.z = gelu_f(v1 + v2);
            v1 = (accC[n4][3] - m1[3]) * r1[3] * l2w + l2b;
            v2 = (accM[n4][3] - m2[3]) * r2[3] * l3w + l3b;
            gv.w = gelu_f(v1 + v2);
        }
        // [o16][px16+pad4] layout: lane writes px=quad*4..+3 of o-row l16
        *(float4*)(tb + l16 * 20 + quad * 4) = gv;
        // same-wave DS ordering: drain writes, fence compiler reordering
        asm volatile("s_waitcnt lgkmcnt(0)" ::: "memory");
        float4 tv = *(const float4*)(tb + o_l * 20 + px4);
        asm volatile("" ::: "memory");
        size_t oi = ((size_t)(batch * NO + n4 * 16 + o_l) << 14) + plocal + px4;
        if (isf32) {
            *(float4*)((float*)out + oi) = tv;
        } else {
            uint_t p0 = (uint_t)f2bf(tv.x) | ((uint_t)f2bf(tv.y) << 16);
            uint_t p1 = (uint_t)f2bf(tv.z) | ((uint_t)f2bf(tv.w) << 16);
            *(uint2*)((ushort_t*)out + oi) = make_uint2(p0, p1);
        }
    }
}

// ---------------------------------------------------------------------------
extern "C" void kernel_launch(void* const* d_in, const int* in_sizes, int n_in,
                              void* d_out, int out_size, void* d_ws, size_t ws_size,
                              hipStream_t stream) {
    const void* x      = d_in[0];
    const void* w1     = d_in[1];
    const void* b1     = d_in[2];
    const void* w2     = d_in[3];
    const void* b2     = d_in[4];
    const void* ln1w   = d_in[5];
    const void* ln1b   = d_in[6];
    const void* conv_w = d_in[7];
    const void* ln2w   = d_in[8];
    const void* ln2b   = d_in[9];
    const void* map_w  = d_in[10];
    const void* map_b  = d_in[11];
    const void* ln3w   = d_in[12];
    const void* ln3b   = d_in[13];

    char* ws = (char*)d_ws;
    ushort_t* xT    = (ushort_t*)(ws);                  // 16,777,216 B
    ushort_t* y1    = (ushort_t*)(ws + 16777216);       // 16,777,216 B
    ushort_t* wfrag = (ushort_t*)(ws + 33554432);       // 131,072 B
    ushort_t* w1b   = (ushort_t*)(ws + 33685504);       //   8,192 B
    ushort_t* w2b   = (ushort_t*)(ws + 33693696);       //  25,600 B
    float*    b1f   = (float*)(ws + 33719296);
    float*    b2f   = (float*)(ws + 33719424);
    float*    ln1wf = (float*)(ws + 33721024);
    float*    ln1bf = (float*)(ws + 33721536);
    float*    mbf   = (float*)(ws + 33722048);
    float*    ln2wf = (float*)(ws + 33723072);
    float*    ln2bf = (float*)(ws + 33724096);
    float*    ln3wf = (float*)(ws + 33725120);
    float*    ln3bf = (float*)(ws + 33726144);
    int*      flag  = (int*)(ws + 33727168);
    const size_t NEED_SMALL = 33727184;
    ushort_t* wkT   = (ushort_t*)(ws + 33727232);       // 52,428,800 B
    const size_t NEED_BIG = 33727232 + (size_t)NKP * NPIX * 2;   // ~86.2 MB

    if (ws_size < NEED_SMALL) {
        int nwords = out_size / 2;
        ksentinel<<<(nwords + 255) / 256, 256, 0, stream>>>((uint_t*)d_out, nwords);
        return;
    }

    kdetect<<<1, 64, 0, stream>>>((const uint_t*)x, flag);
    kprep<<<128, 256, 0, stream>>>(w1, w2, b1, b2, ln1w, ln1b,
                                   ln2w, ln2b, map_b, ln3w, ln3b, flag,
                                   w1b, w2b, b1f, b2f, ln1wf, ln1bf,
                                   ln2wf, ln2bf, mbf, ln3wf, ln3bf);
    kfrag<<<32, 256, 0, stream>>>(conv_w, map_w, flag, wfrag);
    ktrans<<<dim3(8, 128, 4), 256, 0, stream>>>(x, xT, flag);

    if (ws_size >= NEED_BIG) {
        k1a<<<1024, 256, 0, stream>>>(xT, w1b, b1f, w2b, b2f, wkT);
        k1b<<<1024, 512, 0, stream>>>(xT, wkT, ln1wf, ln1bf, y1);
    } else {
        k1_fused<<<dim3(16, 64, 4), 64, 0, stream>>>(xT, w1b, b1f, w2b, b2f,
                                                     ln1wf, ln1bf, y1);
    }

    k23<<<NPIX / 64, 256, 0, stream>>>(y1, xT, wfrag, mbf,
                                       ln2wf, ln2bf, ln3wf, ln3bf, d_out, flag);
}

// Round 2
// 229.857 us; speedup vs baseline: 1.0857x; 1.0188x over previous
//
#include <hip/hip_runtime.h>

typedef unsigned short ushort_t;
typedef unsigned int uint_t;

#define NB 4
#define NC 128
#define NH 128
#define NW 128
#define NPIX 65536   // NB*NH*NW
#define NMID 32
#define NKK 49
#define NK 392
#define NKP 400      // NK padded to 25 n-tiles of 16
#define NO 256
#define LN_EPS 1e-6f

typedef __attribute__((ext_vector_type(8))) short short8;
typedef __attribute__((ext_vector_type(4))) float floatx4;

__device__ __forceinline__ float bf2f(ushort_t u) {
    union { uint_t i; float f; } v; v.i = ((uint_t)u) << 16; return v.f;
}
__device__ __forceinline__ float bf2f_lo(uint_t u) {
    union { uint_t i; float f; } v; v.i = u << 16; return v.f;
}
__device__ __forceinline__ float bf2f_hi(uint_t u) {
    union { uint_t i; float f; } v; v.i = u & 0xffff0000u; return v.f;
}
__device__ __forceinline__ ushort_t f2bf(float f) {
    union { float f; uint_t i; } v; v.f = f;
    uint_t x = v.i;
    uint_t r = (x + 0x7FFFu + ((x >> 16) & 1u)) >> 16;
    return (ushort_t)r;
}
__device__ __forceinline__ float gelu_f(float x) {
    return 0.5f * x * (1.0f + erff(x * 0.70710678118654752f));
}
__device__ __forceinline__ float ldin(const void* p, int i, int isf32) {
    return isf32 ? ((const float*)p)[i] : bf2f(((const ushort_t*)p)[i]);
}
// global -> LDS direct DMA, 16B per lane; LDS dest = uniform base + lane*16
__device__ __forceinline__ void gload_lds16(const void* g, void* l) {
    __builtin_amdgcn_global_load_lds(
        (const __attribute__((address_space(1))) void*)g,
        (__attribute__((address_space(3))) void*)l, 16, 0, 0);
}

// ---------------------------------------------------------------------------
__global__ void kdetect(const uint_t* __restrict__ xw, int* __restrict__ flag) {
    int lane = threadIdx.x;
    int cnt = 0;
    for (int j = 0; j < 8; j++) {
        uint_t w = xw[lane * 8 + j];
        uint_t e = (w >> 7) & 0xffu;
        if (e >= 110u && e <= 135u) cnt++;
    }
    for (int d = 1; d < 64; d <<= 1) cnt += __shfl_xor(cnt, d);
    if (lane == 0) flag[0] = (cnt < 256) ? 1 : 0;
}

__global__ void ksentinel(uint_t* __restrict__ out, int nwords) {
    int i = blockIdx.x * 256 + threadIdx.x;
    if (i < nwords) out[i] = 0x40004000u;
}

// ---------------------------------------------------------------------------
// K0a: transpose x (B,C,H,W) -> xT (B,H,W,C) canonical bf16.
// ---------------------------------------------------------------------------
__global__ __launch_bounds__(256) void ktrans(const void* __restrict__ x,
                                              ushort_t* __restrict__ xT,
                                              const int* __restrict__ flag) {
    int isf32 = flag[0];
    int b = blockIdx.z, h = blockIdx.y;
    int wchunk = blockIdx.x & 1, cchunk = blockIdx.x >> 1;
    int w0 = wchunk << 6, c0 = cchunk << 5;
    __shared__ ushort_t tile[32][66];
    int tx = threadIdx.x & 63, ty = threadIdx.x >> 6;
    for (int r = 0; r < 32; r += 4) {
        int idx = (((b * NC + c0 + r + ty) * NH) + h) * NW + w0 + tx;
        tile[r + ty][tx] = isf32 ? f2bf(((const float*)x)[idx])
                                 : ((const ushort_t*)x)[idx];
    }
    __syncthreads();
    int cc = threadIdx.x & 31, wq = threadIdx.x >> 5;
    for (int pp = 0; pp < 64; pp += 8) {
        int wx = pp + wq;
        xT[((size_t)((b * NH + h) * NW) + w0 + wx) * NC + c0 + cc] = tile[cc][wx];
    }
}

// ---------------------------------------------------------------------------
// K0b: param prep (w1b/w2b for k1a; small vectors -> fp32).
// ---------------------------------------------------------------------------
__global__ __launch_bounds__(256) void kprep(const void* w1, const void* w2,
                                             const void* b1, const void* b2,
                                             const void* ln1w, const void* ln1b,
                                             const void* ln2w, const void* ln2b,
                                             const void* map_b,
                                             const void* ln3w, const void* ln3b,
                                             const int* __restrict__ flag,
                                             ushort_t* __restrict__ w1b,
                                             ushort_t* __restrict__ w2b,
                                             float* __restrict__ b1f,
                                             float* __restrict__ b2f,
                                             float* __restrict__ ln1wf,
                                             float* __restrict__ ln1bf,
                                             float* __restrict__ ln2wf,
                                             float* __restrict__ ln2bf,
                                             float* __restrict__ mbf,
                                             float* __restrict__ ln3wf,
                                             float* __restrict__ ln3bf) {
    int isf32 = flag[0];
    int i = blockIdx.x * 256 + threadIdx.x;
    if (i < NMID * NC) w1b[i] = f2bf(ldin(w1, i, isf32));
    if (i < NKP * NMID) w2b[i] = (i < NK * NMID) ? f2bf(ldin(w2, i, isf32))
                                                 : (ushort_t)0;
    if (i < NMID) b1f[i] = ldin(b1, i, isf32);
    if (i < NKP)  b2f[i] = (i < NK) ? ldin(b2, i, isf32) : 0.f;
    if (i < NC) { ln1wf[i] = ldin(ln1w, i, isf32); ln1bf[i] = ldin(ln1b, i, isf32); }
    if (i < NO) {
        ln2wf[i] = ldin(ln2w, i, isf32); ln2bf[i] = ldin(ln2b, i, isf32);
        mbf[i]   = ldin(map_b, i, isf32);
        ln3wf[i] = ldin(ln3w, i, isf32); ln3bf[i] = ldin(ln3b, i, isf32);
    }
}

// ---------------------------------------------------------------------------
// KFRAG: repack conv_w/map_w into k-block-major MFMA-fragment order for k23:
// chunk id cid = [kb:2][br:1][n4:4][lane:6], chunk = 8 bf16 = 16 B.
// Each kb-tile (2048 chunks = 32 KB) is CONTIGUOUS -> linear global_load_lds
// target in k23. o = n4*16 + (lane&15), ch = kb*32 + (lane>>4)*8 .. +8.
// grid 32 x 256.
// ---------------------------------------------------------------------------
__global__ __launch_bounds__(256) void kfrag(const void* conv_w, const void* map_w,
                                             const int* __restrict__ flag,
                                             ushort_t* __restrict__ wfrag) {
    int isf32 = flag[0];
    int cid = blockIdx.x * 256 + threadIdx.x;   // [0, 8192)
    int lane = cid & 63, n4 = (cid >> 6) & 15, br = (cid >> 10) & 1, kb = cid >> 11;
    int o = n4 * 16 + (lane & 15);
    int ch0 = kb * 32 + (lane >> 4) * 8;
    const void* src = br ? map_w : conv_w;
    ushort_t* dst = wfrag + (size_t)cid * 8;
#pragma unroll
    for (int j = 0; j < 8; j++)
        dst[j] = f2bf(ldin(src, o * NC + ch0 + j, isf32));
}

// ---------------------------------------------------------------------------
// K1a: wk producer (unchanged). grid 1024, block 256.
// ---------------------------------------------------------------------------
__global__ __launch_bounds__(256) void k1a(const ushort_t* __restrict__ xT,
                                           const ushort_t* __restrict__ w1b,
                                           const float* __restrict__ b1f,
                                           const ushort_t* __restrict__ w2b,
                                           const float* __restrict__ b2f,
                                           ushort_t* __restrict__ wkT) {
    __shared__ ushort_t midbuf[64 * 32];
    __shared__ ushort_t wkstage[NKP * 66];

    int t = threadIdx.x;
    int lane = t & 63;
    int w = __builtin_amdgcn_readfirstlane(t >> 6);
    int l16 = lane & 15, quad = lane >> 4;
    int tileid = blockIdx.x;
    int tilex = tileid & 15, tiley = (tileid >> 4) & 15, b = tileid >> 8;
    int h0 = tiley * 8, w0 = tilex * 8;

    int lpx_a = 16 * w + l16;
    int py = lpx_a >> 3, pxx = lpx_a & 7;
    const ushort_t* abase = xT + (size_t)((b * NH + h0 + py) * NW + w0 + pxx) * NC + quad * 8;
    floatx4 am0 = (floatx4)0.f, am1 = (floatx4)0.f;
#pragma unroll
    for (int kb = 0; kb < 4; kb++) {
        short8 a   = *(const short8*)(abase + kb * 32);
        short8 b0  = *(const short8*)(w1b + (l16) * NC + kb * 32 + quad * 8);
        short8 b1v = *(const short8*)(w1b + (16 + l16) * NC + kb * 32 + quad * 8);
        am0 = __builtin_amdgcn_mfma_f32_16x16x32_bf16(a, b0, am0, 0, 0, 0);
        am1 = __builtin_amdgcn_mfma_f32_16x16x32_bf16(a, b1v, am1, 0, 0, 0);
    }
    {
        float bia0 = b1f[l16], bia1 = b1f[16 + l16];
#pragma unroll
        for (int r = 0; r < 4; r++) {
            int m = 16 * w + quad * 4 + r;
            midbuf[m * 32 + l16]      = f2bf(fmaxf(am0[r] + bia0, 0.f));
            midbuf[m * 32 + 16 + l16] = f2bf(fmaxf(am1[r] + bia1, 0.f));
        }
    }
    __syncthreads();

    short8 aM = *(const short8*)(midbuf + (16 * w + l16) * 32 + quad * 8);
#pragma unroll
    for (int nt = 0; nt < 25; nt++) {
        int n = nt * 16 + l16;
        short8 bw = *(const short8*)(w2b + n * 32 + quad * 8);
        floatx4 c = __builtin_amdgcn_mfma_f32_16x16x32_bf16(aM, bw, (floatx4)0.f, 0, 0, 0);
        float bias = b2f[n];
#pragma unroll
        for (int r = 0; r < 4; r++)
            wkstage[n * 66 + 16 * w + quad * 4 + r] = f2bf(c[r] + bias);
    }
    __syncthreads();

    int krow = t >> 5, px2 = t & 31;
    for (int it = 0; it < 50; it++) {
        int k = it * 8 + krow;
        uint_t v = *(const uint_t*)&wkstage[k * 66 + 2 * px2];
        *(uint_t*)&wkT[(size_t)k * NPIX + tileid * 64 + 2 * px2] = v;
    }
}

// ---------------------------------------------------------------------------
// K1b v3 (unchanged from round 8). grid 1024, block 512.
// ---------------------------------------------------------------------------
__global__ __launch_bounds__(512) void k1b(const ushort_t* __restrict__ xT,
                                           const ushort_t* __restrict__ wkT,
                                           const float* __restrict__ ln1wf,
                                           const float* __restrict__ ln1bf,
                                           ushort_t* __restrict__ y1) {
    __shared__ __align__(16) char smem[50432];
    uint4* x8   = (uint4*)smem;
    float* sred = (float*)smem;

    int t = threadIdx.x;
    int lane = t & 63;
    int w = __builtin_amdgcn_readfirstlane(t >> 6);
    int tileid = blockIdx.x;
    int tilex = tileid & 15, tiley = (tileid >> 4) & 15, b = tileid >> 8;
    int h0 = tiley * 8, w0 = tilex * 8;
    int py = lane >> 3, pxx = lane & 7;

    const ushort_t* wkbase = wkT + (size_t)(w * NKK) * NPIX + tileid * 64 + lane;
    uint_t wkp[25];
#pragma unroll
    for (int j = 0; j < 24; j++) {
        uint_t lo = wkbase[(size_t)(2 * j) * NPIX];
        uint_t hi = wkbase[(size_t)(2 * j + 1) * NPIX];
        wkp[j] = lo | (hi << 16);
    }
    wkp[24] = wkbase[(size_t)48 * NPIX];

    for (int it = 0; it < 7; it++) {
        int idx = it * 512 + t;
        if (idx < 3136) {
            int oct = idx & 15, hp = idx >> 4;
            int hy = hp / 14, hx = hp - hy * 14;
            int gh = h0 + hy - 3, gw = w0 + hx - 3;
            uint4 v = make_uint4(0u, 0u, 0u, 0u);
            if ((unsigned)gh < (unsigned)NH && (unsigned)gw < (unsigned)NW) {
                v = *(const uint4*)&xT[(size_t)((b * NH + gh) * NW + gw) * NC + 8 * oct];
            }
            x8[oct * 197 + hp] = v;
        }
    }
    __syncthreads();

    int base0 = py * 14 + pxx;
    float a[16];
#pragma unroll
    for (int j = 0; j < 16; j++) a[j] = 0.f;

#pragma unroll
    for (int tap = 0; tap < NKK; tap++) {
        float wkf = (tap & 1) ? bf2f((ushort_t)(wkp[tap >> 1] >> 16))
                              : bf2f((ushort_t)(wkp[tap >> 1] & 0xffffu));
        int xa = base0 + (tap / 7) * 14 + (tap % 7);
        uint4 u0 = x8[(2 * w) * 197 + xa];
        uint4 u1 = x8[(2 * w + 1) * 197 + xa];
        a[0]  = fmaf(wkf, bf2f_lo(u0.x), a[0]);
        a[1]  = fmaf(wkf, bf2f_hi(u0.x), a[1]);
        a[2]  = fmaf(wkf, bf2f_lo(u0.y), a[2]);
        a[3]  = fmaf(wkf, bf2f_hi(u0.y), a[3]);
        a[4]  = fmaf(wkf, bf2f_lo(u0.z), a[4]);
        a[5]  = fmaf(wkf, bf2f_hi(u0.z), a[5]);
        a[6]  = fmaf(wkf, bf2f_lo(u0.w), a[6]);
        a[7]  = fmaf(wkf, bf2f_hi(u0.w), a[7]);
        a[8]  = fmaf(wkf, bf2f_lo(u1.x), a[8]);
        a[9]  = fmaf(wkf, bf2f_hi(u1.x), a[9]);
        a[10] = fmaf(wkf, bf2f_lo(u1.y), a[10]);
        a[11] = fmaf(wkf, bf2f_hi(u1.y), a[11]);
        a[12] = fmaf(wkf, bf2f_lo(u1.z), a[12]);
        a[13] = fmaf(wkf, bf2f_hi(u1.z), a[13]);
        a[14] = fmaf(wkf, bf2f_lo(u1.w), a[14]);
        a[15] = fmaf(wkf, bf2f_hi(u1.w), a[15]);
    }
    __syncthreads();

    float s = 0.f, sq = 0.f;
#pragma unroll
    for (int j = 0; j < 16; j++) { s += a[j]; sq += a[j] * a[j]; }
    sred[(w * 64 + lane) * 2]     = s;
    sred[(w * 64 + lane) * 2 + 1] = sq;
    __syncthreads();
    float ts = 0.f, tq = 0.f;
#pragma unroll
    for (int r = 0; r < 8; r++) {
        ts += sred[(r * 64 + lane) * 2];
        tq += sred[(r * 64 + lane) * 2 + 1];
    }
    float mean = ts * (1.0f / NC);
    float var = tq * (1.0f / NC) - mean * mean;
    float rstd = rsqrtf(var + LN_EPS);

    int p = (b * NH + h0 + py) * NW + w0 + pxx;
    uint_t pk[8];
#pragma unroll
    for (int j = 0; j < 8; j++) {
        int c0 = 16 * w + 2 * j;
        float g0 = gelu_f((a[2 * j] - mean) * rstd * ln1wf[c0] + ln1bf[c0]);
        float g1 = gelu_f((a[2 * j + 1] - mean) * rstd * ln1wf[c0 + 1] + ln1bf[c0 + 1]);
        pk[j] = (uint_t)f2bf(g0) | ((uint_t)f2bf(g1) << 16);
    }
    uint4* dst = (uint4*)(y1 + (size_t)p * NC + 16 * w);
    dst[0] = make_uint4(pk[0], pk[1], pk[2], pk[3]);
    dst[1] = make_uint4(pk[4], pk[5], pk[6], pk[7]);
}

// ---------------------------------------------------------------------------
// K1 fused fallback — used only if ws too small for wkT.
// ---------------------------------------------------------------------------
__global__ __launch_bounds__(64) void k1_fused(const ushort_t* __restrict__ xT,
                                               const ushort_t* __restrict__ w1b,
                                               const float* __restrict__ b1f,
                                               const ushort_t* __restrict__ w2b,
                                               const float* __restrict__ b2f,
                                               const float* __restrict__ ln1wf,
                                               const float* __restrict__ ln1bf,
                                               ushort_t* __restrict__ y1) {
    __shared__ ushort_t midbuf[16 * 32];
    __shared__ ushort_t wkbuf[16 * NKP];

    int lane = threadIdx.x;
    int l16 = lane & 15, quad = lane >> 4;
    int b = blockIdx.z;
    int h0 = blockIdx.y * 2, w0 = blockIdx.x * 8;

    int Pa = (b * NH + h0 + (l16 >> 3)) * NW + w0 + (l16 & 7);
    const ushort_t* abase = xT + (size_t)Pa * NC + quad * 8;
    floatx4 am0 = (floatx4)0.f, am1 = (floatx4)0.f;
#pragma unroll
    for (int kb = 0; kb < 4; kb++) {
        short8 a   = *(const short8*)(abase + kb * 32);
        short8 b0  = *(const short8*)(w1b + (l16) * NC + kb * 32 + quad * 8);
        short8 b1v = *(const short8*)(w1b + (16 + l16) * NC + kb * 32 + quad * 8);
        am0 = __builtin_amdgcn_mfma_f32_16x16x32_bf16(a, b0, am0, 0, 0, 0);
        am1 = __builtin_amdgcn_mfma_f32_16x16x32_bf16(a, b1v, am1, 0, 0, 0);
    }
    {
        float bia0 = b1f[l16], bia1 = b1f[16 + l16];
#pragma unroll
        for (int r = 0; r < 4; r++) {
            int m = quad * 4 + r;
            midbuf[m * 32 + l16]      = f2bf(fmaxf(am0[r] + bia0, 0.f));
            midbuf[m * 32 + 16 + l16] = f2bf(fmaxf(am1[r] + bia1, 0.f));
        }
    }
    __syncthreads();

    short8 aM = *(const short8*)(midbuf + l16 * 32 + quad * 8);
#pragma unroll
    for (int nt = 0; nt < 25; nt++) {
        int n = nt * 16 + l16;
        short8 bw = *(const short8*)(w2b + n * 32 + quad * 8);
        floatx4 c = __builtin_amdgcn_mfma_f32_16x16x32_bf16(aM, bw, (floatx4)0.f, 0, 0, 0);
        float bias = b2f[n];
#pragma unroll
        for (int r = 0; r < 4; r++)
            wkbuf[(quad * 4 + r) * NKP + n] = f2bf(c[r] + bias);
    }
    __syncthreads();

    int g = lane >> 3;
    float l1w0 = ln1wf[2 * lane], l1w1 = ln1wf[2 * lane + 1];
    float l1b0 = ln1bf[2 * lane], l1b1 = ln1bf[2 * lane + 1];

    for (int i = 0; i < 16; i++) {
        int hh0 = h0 + (i >> 3), ww0 = w0 + (i & 7);
        int p = (b * NH + hh0) * NW + ww0;
        const ushort_t* wkrow = wkbuf + i * NKP + g * NKK;
        float a0 = 0.f, a1 = 0.f;
#pragma unroll
        for (int dy = -3; dy <= 3; dy++) {
            int hh = hh0 + dy;
            if ((unsigned)hh >= (unsigned)NH) continue;
#pragma unroll
            for (int dx = -3; dx <= 3; dx++) {
                int ww = ww0 + dx;
                if ((unsigned)ww >= (unsigned)NW) continue;
                float wkv = bf2f(wkrow[(dy + 3) * 7 + (dx + 3)]);
                uint_t xp = *(const uint_t*)(xT + ((size_t)(p + dy * NW + dx)) * NC + 2 * lane);
                a0 = fmaf(wkv, bf2f((ushort_t)(xp & 0xffffu)), a0);
                a1 = fmaf(wkv, bf2f((ushort_t)(xp >> 16)), a1);
            }
        }
        float s = a0 + a1, sq = a0 * a0 + a1 * a1;
#pragma unroll
        for (int d = 1; d < 64; d <<= 1) {
            s  += __shfl_xor(s, d);
            sq += __shfl_xor(sq, d);
        }
        float mean = s * (1.0f / NC);
        float var = sq * (1.0f / NC) - mean * mean;
        float rstd = rsqrtf(var + LN_EPS);
        float g0 = gelu_f((a0 - mean) * rstd * l1w0 + l1b0);
        float g1 = gelu_f((a1 - mean) * rstd * l1w1 + l1b1);
        uint_t pk = (uint_t)f2bf(g0) | ((uint_t)f2bf(g1) << 16);
        *(uint_t*)(y1 + (size_t)p * NC + 2 * lane) = pk;
    }
}

// ---------------------------------------------------------------------------
// K23 v6: LDS-staged B (double-buffered 2x32KB via global_load_lds DMA) so
// the inner loop reads B with low-latency conflict-free ds_read_b128 instead
// of 128 L2 loads per wave (true reg footprint ~256/lane -> only 2 waves/SIMD;
// latency must be removed, not hidden). A operands hoisted to regs up front
// (per-kb MFMA phase has zero global deps). One __syncthreads per kb; compiler
// emits the vmcnt(0) drain before s_barrier. Epilogue: direct per-lane
// float4/uint2 stores (acc[n4][r] covers 4 contiguous px) -> no LDS transpose,
// no lgkmcnt drains. Wave-autonomous LN unchanged. grid 1024, block 256.
// ---------------------------------------------------------------------------
__global__ __launch_bounds__(256, 2) void k23(const ushort_t* __restrict__ y1,
                                              const ushort_t* __restrict__ xT,
                                              const ushort_t* __restrict__ wfrag,
                                              const float* __restrict__ mbf,
                                              const float* __restrict__ ln2wf,
                                              const float* __restrict__ ln2bf,
                                              const float* __restrict__ ln3wf,
                                              const float* __restrict__ ln3bf,
                                              void* __restrict__ out,
                                              const int* __restrict__ flag) {
    __shared__ __align__(16) char sbuf[65536];   // 2 x 32KB B double-buffer

    int isf32 = flag[0];
    int t = threadIdx.x;
    int lane = t & 63;
    int w = __builtin_amdgcn_readfirstlane(t >> 6);
    int quad = lane >> 4, l16 = lane & 15;

    int P0 = blockIdx.x * 64;
    int pw = P0 + w * 16;                       // this wave's first pixel
    const ushort_t* aYp = y1 + (size_t)(pw + l16) * NC + quad * 8;
    const ushort_t* aXp = xT + (size_t)(pw + l16) * NC + quad * 8;

    // stage kb=0 B-tile (32KB, chunks [0,2048)): wave w covers w*512 + i*64 + lane
    {
        const ushort_t* gsrc = wfrag + (size_t)(w * 512 + lane) * 8;
        char* ldst = sbuf + (size_t)(w * 512) * 16;
#pragma unroll
        for (int i = 0; i < 8; i++)
            gload_lds16(gsrc + i * 64 * 8, ldst + i * 64 * 16);
    }
    // A operands for all 4 k-blocks, hoisted to registers
    short8 aYr[4], aXr[4];
#pragma unroll
    for (int kb = 0; kb < 4; kb++) {
        aYr[kb] = *(const short8*)(aYp + kb * 32);
        aXr[kb] = *(const short8*)(aXp + kb * 32);
    }
    __syncthreads();

    floatx4 accC[16], accM[16];
#pragma unroll
    for (int n4 = 0; n4 < 16; n4++) { accC[n4] = (floatx4)0.f; accM[n4] = (floatx4)0.f; }

#pragma unroll
    for (int kb = 0; kb < 4; kb++) {
        const char* bufr = sbuf + (kb & 1) * 32768;
        if (kb < 3) {
            // prefetch next kb-tile into the other buffer; stays in flight
            // across the MFMA phase, drained at the trailing barrier.
            char* bufw = sbuf + ((kb + 1) & 1) * 32768;
            const ushort_t* gsrc = wfrag + ((size_t)(kb + 1) * 2048 + w * 512 + lane) * 8;
            char* ldst = bufw + (size_t)(w * 512) * 16;
#pragma unroll
            for (int i = 0; i < 8; i++)
                gload_lds16(gsrc + i * 64 * 8, ldst + i * 64 * 16);
        }
        short8 aY = aYr[kb], aX = aXr[kb];
#pragma unroll
        for (int n4 = 0; n4 < 16; n4++) {
            // chunk-local = br*1024 + n4*64 + lane, 16 B each; stride-1 b128
            short8 bc = *(const short8*)(bufr + (size_t)(n4 * 64 + lane) * 16);
            short8 bm = *(const short8*)(bufr + (size_t)(1024 + n4 * 64 + lane) * 16);
            accC[n4] = __builtin_amdgcn_mfma_f32_16x16x32_bf16(aY, bc, accC[n4], 0, 0, 0);
            accM[n4] = __builtin_amdgcn_mfma_f32_16x16x32_bf16(aX, bm, accM[n4], 0, 0, 0);
        }
        if (kb < 3) __syncthreads();
    }

    // map-branch bias (before LN3 stats)
#pragma unroll
    for (int n4 = 0; n4 < 16; n4++) {
        float mb = mbf[n4 * 16 + l16];
#pragma unroll
        for (int r = 0; r < 4; r++) accM[n4][r] += mb;
    }

    // LN stats per px (px = quad*4 + r): 16-reg partial sums, then butterfly
    // over the 16 o-lanes (d<16 stays inside each l16 group).
    floatx4 s1 = (floatx4)0.f, q1 = (floatx4)0.f, s2 = (floatx4)0.f, q2 = (floatx4)0.f;
#pragma unroll
    for (int n4 = 0; n4 < 16; n4++)
#pragma unroll
        for (int r = 0; r < 4; r++) {
            float a = accC[n4][r], m = accM[n4][r];
            s1[r] += a; q1[r] += a * a;
            s2[r] += m; q2[r] += m * m;
        }
#pragma unroll
    for (int d = 1; d < 16; d <<= 1) {
#pragma unroll
        for (int r = 0; r < 4; r++) {
            s1[r] += __shfl_xor(s1[r], d);
            q1[r] += __shfl_xor(q1[r], d);
            s2[r] += __shfl_xor(s2[r], d);
            q2[r] += __shfl_xor(q2[r], d);
        }
    }
    floatx4 m1, r1, m2, r2;
#pragma unroll
    for (int r = 0; r < 4; r++) {
        m1[r] = s1[r] * (1.0f / NO);
        r1[r] = rsqrtf(q1[r] * (1.0f / NO) - m1[r] * m1[r] + LN_EPS);
        m2[r] = s2[r] * (1.0f / NO);
        r2[r] = rsqrtf(q2[r] * (1.0f / NO) - m2[r] * m2[r] + LN_EPS);
    }

    // Direct stores: lane holds (o = n4*16+l16, px = quad*4 + 0..3) which is
    // 4 CONTIGUOUS pixels in the [B][O][H][W] output -> float4/uint2 per n4.
    int batch = pw >> 14;
    int plocal = (pw & 16383) + quad * 4;
#pragma unroll
    for (int n4 = 0; n4 < 16; n4++) {
        int o = n4 * 16 + l16;
        float l2w = ln2wf[o], l2b = ln2bf[o];
        float l3w = ln3wf[o], l3b = ln3bf[o];
        float4 gv;
        {
            float v1, v2;
            v1 = (accC[n4][0] - m1[0]) * r1[0] * l2w + l2b;
            v2 = (accM[n4][0] - m2[0]) * r2[0] * l3w + l3b;
            gv.x = gelu_f(v1 + v2);
            v1 = (accC[n4][1] - m1[1]) * r1[1] * l2w + l2b;
            v2 = (accM[n4][1] - m2[1]) * r2[1] * l3w + l3b;
            gv.y = gelu_f(v1 + v2);
            v1 = (accC[n4][2] - m1[2]) * r1[2] * l2w + l2b;
            v2 = (accM[n4][2] - m2[2]) * r2[2] * l3w + l3b;
            gv.z = gelu_f(v1 + v2);
            v1 = (accC[n4][3] - m1[3]) * r1[3] * l2w + l2b;
            v2 = (accM[n4][3] - m2[3]) * r2[3] * l3w + l3b;
            gv.w = gelu_f(v1 + v2);
        }
        size_t oi = ((size_t)(batch * NO + o) << 14) + plocal;
        if (isf32) {
            *(float4*)((float*)out + oi) = gv;
        } else {
            uint_t p0 = (uint_t)f2bf(gv.x) | ((uint_t)f2bf(gv.y) << 16);
            uint_t p1 = (uint_t)f2bf(gv.z) | ((uint_t)f2bf(gv.w) << 16);
            *(uint2*)((ushort_t*)out + oi) = make_uint2(p0, p1);
        }
    }
}

// ---------------------------------------------------------------------------
extern "C" void kernel_launch(void* const* d_in, const int* in_sizes, int n_in,
                              void* d_out, int out_size, void* d_ws, size_t ws_size,
                              hipStream_t stream) {
    const void* x      = d_in[0];
    const void* w1     = d_in[1];
    const void* b1     = d_in[2];
    const void* w2     = d_in[3];
    const void* b2     = d_in[4];
    const void* ln1w   = d_in[5];
    const void* ln1b   = d_in[6];
    const void* conv_w = d_in[7];
    const void* ln2w   = d_in[8];
    const void* ln2b   = d_in[9];
    const void* map_w  = d_in[10];
    const void* map_b  = d_in[11];
    const void* ln3w   = d_in[12];
    const void* ln3b   = d_in[13];

    char* ws = (char*)d_ws;
    ushort_t* xT    = (ushort_t*)(ws);                  // 16,777,216 B
    ushort_t* y1    = (ushort_t*)(ws + 16777216);       // 16,777,216 B
    ushort_t* wfrag = (ushort_t*)(ws + 33554432);       // 131,072 B
    ushort_t* w1b   = (ushort_t*)(ws + 33685504);       //   8,192 B
    ushort_t* w2b   = (ushort_t*)(ws + 33693696);       //  25,600 B
    float*    b1f   = (float*)(ws + 33719296);
    float*    b2f   = (float*)(ws + 33719424);
    float*    ln1wf = (float*)(ws + 33721024);
    float*    ln1bf = (float*)(ws + 33721536);
    float*    mbf   = (float*)(ws + 33722048);
    float*    ln2wf = (float*)(ws + 33723072);
    float*    ln2bf = (float*)(ws + 33724096);
    float*    ln3wf = (float*)(ws + 33725120);
    float*    ln3bf = (float*)(ws + 33726144);
    int*      flag  = (int*)(ws + 33727168);
    const size_t NEED_SMALL = 33727184;
    ushort_t* wkT   = (ushort_t*)(ws + 33727232);       // 52,428,800 B
    const size_t NEED_BIG = 33727232 + (size_t)NKP * NPIX * 2;   // ~86.2 MB

    if (ws_size < NEED_SMALL) {
        int nwords = out_size / 2;
        ksentinel<<<(nwords + 255) / 256, 256, 0, stream>>>((uint_t*)d_out, nwords);
        return;
    }

    kdetect<<<1, 64, 0, stream>>>((const uint_t*)x, flag);
    kprep<<<128, 256, 0, stream>>>(w1, w2, b1, b2, ln1w, ln1b,
                                   ln2w, ln2b, map_b, ln3w, ln3b, flag,
                                   w1b, w2b, b1f, b2f, ln1wf, ln1bf,
                                   ln2wf, ln2bf, mbf, ln3wf, ln3bf);
    kfrag<<<32, 256, 0, stream>>>(conv_w, map_w, flag, wfrag);
    ktrans<<<dim3(8, 128, 4), 256, 0, stream>>>(x, xT, flag);

    if (ws_size >= NEED_BIG) {
        k1a<<<1024, 256, 0, stream>>>(xT, w1b, b1f, w2b, b2f, wkT);
        k1b<<<1024, 512, 0, stream>>>(xT, wkT, ln1wf, ln1bf, y1);
    } else {
        k1_fused<<<dim3(16, 64, 4), 64, 0, stream>>>(xT, w1b, b1f, w2b, b2f,
                                                     ln1wf, ln1bf, y1);
    }

    k23<<<NPIX / 64, 256, 0, stream>>>(y1, xT, wfrag, mbf,
                                       ln2wf, ln2bf, ln3wf, ln3bf, d_out, flag);
}